// Round 1
// baseline (904.047 us; speedup 1.0000x reference)
//
#include <hip/hip_runtime.h>

#define H 512
#define TSTEPS 196
#define FLEN 784
#define NBATCH 256

// workspace layout (floats):
//   [0)        WT_h2h1  512*512   (WT[k*512+j] = W[j*512+k])
//   [262144)   WT_i2h2  512*512
//   [524288)   WT_h2h2  512*512
//   [786432)   WT_i2h3  512*512
//   [1048576)  m1T      196*512   (mT[t*512+j] = m[j*784+t])
//   [1148928)  m2T      196*512
//   [1249280)  m3T      196*512

__global__ void transpose4(const float* __restrict__ a,
                           const float* __restrict__ b,
                           const float* __restrict__ c,
                           const float* __restrict__ d,
                           float* __restrict__ ws)
{
    __shared__ float tile[32][33];
    const float* src = (blockIdx.z == 0) ? a : (blockIdx.z == 1) ? b
                     : (blockIdx.z == 2) ? c : d;
    float* dst = ws + (size_t)blockIdx.z * (H * H);
    int bx = blockIdx.x * 32, by = blockIdx.y * 32;
    int tx = threadIdx.x, ty = threadIdx.y;
    for (int r = ty; r < 32; r += 8)
        tile[r][tx] = src[(by + r) * H + bx + tx];
    __syncthreads();
    for (int r = ty; r < 32; r += 8)
        dst[(bx + r) * H + by + tx] = tile[tx][r];
}

__global__ void maskT3(const float* __restrict__ m1, const float* __restrict__ m2,
                       const float* __restrict__ m3, float* __restrict__ mt)
{
    int idx = blockIdx.x * 256 + threadIdx.x;
    if (idx >= TSTEPS * H) return;
    const float* src = (blockIdx.z == 0) ? m1 : (blockIdx.z == 1) ? m2 : m3;
    float* dst = mt + (size_t)blockIdx.z * (TSTEPS * H);
    int t = idx >> 9, j = idx & (H - 1);
    dst[idx] = src[j * FLEN + t];
}

// deterministic active-index compaction (ascending k): ballot + fixed wave prefix
__device__ __forceinline__ void rebuild(float s, int j, int lane, int wid,
                                        int* list, int* wcnt, int* nact)
{
    unsigned long long ball = __ballot(s != 0.0f);
    int cnt = __popcll(ball);
    if (lane == 0) wcnt[wid] = cnt;
    __syncthreads();
    int base = 0;
#pragma unroll
    for (int w = 0; w < 8; ++w)
        if (w < wid) base += wcnt[w];
    if (s != 0.0f) {
        int pre = __popcll(ball & ((1ull << lane) - 1ull));
        list[base + pre] = j;
    }
    if (j == 0) {
        int tot = 0;
#pragma unroll
        for (int w = 0; w < 8; ++w) tot += wcnt[w];
        *nact = tot;
    }
}

// h[j] += sum over active k of WT[k][j]; 4 accumulators, deterministic order
__device__ __forceinline__ float gather(const float* __restrict__ WT,
                                        const int* __restrict__ list,
                                        int nact, int j)
{
    float a0 = 0.f, a1 = 0.f, a2 = 0.f, a3 = 0.f;
    int i = 0;
    for (; i + 4 <= nact; i += 4) {
        int k0 = list[i + 0], k1 = list[i + 1];
        int k2 = list[i + 2], k3 = list[i + 3];
        a0 += WT[(k0 << 9) + j];
        a1 += WT[(k1 << 9) + j];
        a2 += WT[(k2 << 9) + j];
        a3 += WT[(k3 << 9) + j];
    }
    for (; i < nact; ++i)
        a0 += WT[(list[i] << 9) + j];
    return (a0 + a1) + (a2 + a3);
}

__global__ __launch_bounds__(512)
void lsnn_main(const float* __restrict__ x,
               const float* __restrict__ Wi1,
               const float* __restrict__ bi1, const float* __restrict__ bh1,
               const float* __restrict__ bi2, const float* __restrict__ bh2,
               const float* __restrict__ bi3,
               const float* __restrict__ Wo,  const float* __restrict__ bo,
               const float* __restrict__ tau1, const float* __restrict__ tau2,
               const float* __restrict__ tau3,
               const float* __restrict__ ws,
               float* __restrict__ out)
{
    const float* WT1  = ws;                    // W_h2h1^T
    const float* WTi2 = ws + 262144;           // W_i2h2^T
    const float* WTh2 = ws + 524288;           // W_h2h2^T
    const float* WTi3 = ws + 786432;           // W_i2h3^T
    const float* m1T  = ws + 1048576;
    const float* m2T  = m1T + TSTEPS * H;
    const float* m3T  = m2T + TSTEPS * H;

    const int n = blockIdx.x;
    const int j = threadIdx.x;
    const int lane = j & 63, wid = j >> 6;

    __shared__ int list1[H], list2[H];
    __shared__ int wcnt[8];
    __shared__ int nact1s, nact2s;
    __shared__ float c3s[H];

    float4 wi = reinterpret_cast<const float4*>(Wi1)[j];
    float bs1 = bi1[j] + bh1[j];
    float bs2 = bi2[j] + bh2[j];
    float bs3 = bi3[j];
    float ro1 = expf(-1.0f / tau1[j]);
    float ro2 = expf(-1.0f / tau2[j]);
    float ro3 = expf(-1.0f / tau3[j]);
    const float alpha = expf(-1.0f / 20.0f);
    const float oma = 1.0f - alpha;

    float mem1 = 0.f, mem2 = 0.f, mem3 = 0.f;
    float b1 = 0.01f, b2 = 0.01f, b3 = 0.01f;
    float s1 = 0.f, s2 = 0.f, s3 = 0.f;
    float cnt3 = 0.f;

    if (j == 0) { nact1s = 0; nact2s = 0; }
    __syncthreads();

    const float* xr = x + n * FLEN;

    for (int t = 0; t < TSTEPS; ++t) {
        int base = (t < 48) ? (4 * t) : (FLEN - 4);
        float xv0 = xr[base + 0], xv1 = xr[base + 1];
        float xv2 = xr[base + 2], xv3 = xr[base + 3];
        float mk1 = m1T[t * H + j];
        float mk2 = m2T[t * H + j];
        float mk3 = m3T[t * H + j];

        int na1 = nact1s;   // old s1 list (for recurrent h1)
        int na2 = nact2s;   // old s2 list (for recurrent h2)

        // ---- layer 1: h1 = x@Wi1^T + bi1 + s1_old@Wh1^T + bh1 ----
        float h1 = wi.x * xv0 + wi.y * xv1 + wi.z * xv2 + wi.w * xv3 + bs1
                 + gather(WT1, list1, na1, j);
        b1 = ro1 * b1 + (1.0f - ro1) * s1;
        float Bth1 = 0.01f + 1.8f * b1;
        float nm1 = mem1 * alpha + oma * h1 - Bth1 * s1;
        mem1 = (mk1 == 0.0f) ? mem1 : nm1;
        s1 = (mem1 - Bth1 > 0.0f) ? mk1 : 0.0f;

        __syncthreads();                                  // list1 readers done
        rebuild(s1, j, lane, wid, list1, wcnt, &nact1s);  // internal sync
        __syncthreads();                                  // new list1 ready
        int na1n = nact1s;

        // ---- layer 2: h2 = s1_new@Wi2^T + bi2 + s2_old@Wh2^T + bh2 ----
        float h2 = bs2 + gather(WTi2, list1, na1n, j)
                       + gather(WTh2, list2, na2, j);
        b2 = ro2 * b2 + (1.0f - ro2) * s2;
        float Bth2 = 0.01f + 1.8f * b2;
        float nm2 = mem2 * alpha + oma * h2 - Bth2 * s2;
        mem2 = (mk2 == 0.0f) ? mem2 : nm2;
        s2 = (mem2 - Bth2 > 0.0f) ? mk2 : 0.0f;

        __syncthreads();                                  // list2 readers done
        rebuild(s2, j, lane, wid, list2, wcnt, &nact2s);  // internal sync
        __syncthreads();                                  // new list2 ready
        int na2n = nact2s;

        // ---- layer 3: h3 = s2_new@Wi3^T + bi3 ----
        float h3 = bs3 + gather(WTi3, list2, na2n, j);
        b3 = ro3 * b3 + (1.0f - ro3) * s3;
        float Bth3 = 0.01f + 1.8f * b3;
        float nm3 = mem3 * alpha + oma * h3 - Bth3 * s3;
        mem3 = (mk3 == 0.0f) ? mem3 : nm3;
        s3 = (mem3 - Bth3 > 0.0f) ? mk3 : 0.0f;
        cnt3 += s3;   // defer output GEMV: acc = Wo @ sum_t s3(t)
    }

    // ---- output: out[n,o] = (Wo[o,:]·cnt3 + T*bo[o]) / T ----
    c3s[j] = cnt3;
    __syncthreads();
    for (int o = wid; o < 10; o += 8) {
        float p = 0.0f;
        for (int i = lane; i < H; i += 64)
            p += Wo[o * H + i] * c3s[i];
        for (int off = 32; off > 0; off >>= 1)
            p += __shfl_down(p, off);
        if (lane == 0)
            out[n * 10 + o] = (p + 196.0f * bo[o]) / 196.0f;
    }
}

extern "C" void kernel_launch(void* const* d_in, const int* in_sizes, int n_in,
                              void* d_out, int out_size, void* d_ws, size_t ws_size,
                              hipStream_t stream)
{
    const float* x    = (const float*)d_in[0];
    const float* Wi1  = (const float*)d_in[1];
    const float* bi1  = (const float*)d_in[2];
    const float* Wh1  = (const float*)d_in[3];
    const float* bh1  = (const float*)d_in[4];
    const float* Wi2  = (const float*)d_in[5];
    const float* bi2  = (const float*)d_in[6];
    const float* Wh2  = (const float*)d_in[7];
    const float* bh2  = (const float*)d_in[8];
    const float* Wi3  = (const float*)d_in[9];
    const float* bi3  = (const float*)d_in[10];
    const float* Wo   = (const float*)d_in[11];
    const float* bo   = (const float*)d_in[12];
    const float* tau1 = (const float*)d_in[13];
    const float* tau2 = (const float*)d_in[14];
    const float* tau3 = (const float*)d_in[15];
    const float* m1   = (const float*)d_in[16];
    const float* m2   = (const float*)d_in[17];
    const float* m3   = (const float*)d_in[18];

    float* ws  = (float*)d_ws;
    float* out = (float*)d_out;

    // pre-pass: transpose the 4 recurrent/ff matrices + 3 masks into ws
    transpose4<<<dim3(16, 16, 4), dim3(32, 8, 1), 0, stream>>>(Wh1, Wi2, Wh2, Wi3, ws);
    maskT3<<<dim3((TSTEPS * H + 255) / 256, 1, 3), 256, 0, stream>>>(m1, m2, m3, ws + 1048576);

    // main persistent kernel: 1 sample per workgroup (256 WGs, 512 thr)
    lsnn_main<<<NBATCH, H, 0, stream>>>(x, Wi1, bi1, bh1, bi2, bh2, bi3,
                                        Wo, bo, tau1, tau2, tau3, ws, out);
}